// Round 13
// baseline (383.467 us; speedup 1.0000x reference)
//
#include <hip/hip_runtime.h>
#include <cstdint>
#include <cstddef>

typedef __attribute__((ext_vector_type(8))) short bfrag;    // 8 bf16 (4 VGPR)
typedef __attribute__((ext_vector_type(4))) float f4;       // 16x16 MFMA C/D
typedef __attribute__((ext_vector_type(16))) float f16v;    // 32x32 MFMA C/D

#define MFMA16(a, b, c) __builtin_amdgcn_mfma_f32_16x16x32_bf16(a, b, c, 0, 0, 0)
#define MFMA32(a, b, c) __builtin_amdgcn_mfma_f32_32x32x16_bf16(a, b, c, 0, 0, 0)

// ---------------------------------------------------------------------------
// fp32 -> bf16 RNE, and hi/lo split helpers
// ---------------------------------------------------------------------------
__device__ __forceinline__ unsigned short f2bf(float x) {
  unsigned u = __float_as_uint(x);
  u += 0x7fffu + ((u >> 16) & 1u);
  return (unsigned short)(u >> 16);
}
__device__ __forceinline__ float bf2f(unsigned short h) {
  return __uint_as_float(((unsigned)h) << 16);
}
// HW packed f32->2xbf16 (one instr). Rounding-mode-agnostic use: the lo
// residue compensates whatever hi rounds to.
__device__ __forceinline__ unsigned cvt_pk_bf16(float a, float b) {
  unsigned r;
  asm("v_cvt_pk_bf16_f32 %0, %1, %2" : "=v"(r) : "v"(a), "v"(b));
  return r;
}
// One-instruction cross-half exchange: a' = [a_lo | b_lo], b' = [a_hi | b_hi].
__device__ __forceinline__ void permswap(unsigned& a, unsigned& b) {
  auto r = __builtin_amdgcn_permlane32_swap((int)a, (int)b, false, false);
  a = (unsigned)r[0];
  b = (unsigned)r[1];
}
// Async global->LDS, 16B per lane. Dest is wave-uniform base + lane*16.
__device__ __forceinline__ void gl16(const unsigned short* g, unsigned short* l) {
  __builtin_amdgcn_global_load_lds(
      (const __attribute__((address_space(1))) unsigned int*)g,
      (__attribute__((address_space(3))) unsigned int*)l, 16, 0, 0);
}

// ---------------------------------------------------------------------------
// Software-exact OCP e4m3fn rounding (RTNE via magic-add; matches ml_dtypes
// bit-exact incl. subnormal grid 2^-9 and the 448-saturation region).
// ---------------------------------------------------------------------------
__device__ __forceinline__ float qd_e4m3(float v) {
  float a = fabsf(v);
  unsigned u = __float_as_uint(a);
  int e = (int)(u >> 23) - 127;
  int k = e - 3;
  if (k < -9) k = -9;
  float big = __uint_as_float((unsigned)(k + 150) << 23);  // 2^(k+23)
  float r = (a + big) - big;
  return __builtin_copysignf(r, v);
}

// ---------------------------------------------------------------------------
// Activation quant: per 128-block, emit e4m3 CODES as bf16 (exact) + scale.
// ---------------------------------------------------------------------------
__global__ __launch_bounds__(256) void quant_x(const float* __restrict__ src,
                                               unsigned short* __restrict__ q,
                                               float* __restrict__ s,
                                               int nblk) {
  int gid = blockIdx.x * 256 + threadIdx.x;
  int wid = gid >> 6;
  int lane = gid & 63;
  if (wid >= nblk) return;
  size_t off = (size_t)wid * 128 + lane * 2;
  float2 xv = *reinterpret_cast<const float2*>(src + off);
  float m = fmaxf(fabsf(xv.x), fabsf(xv.y));
#pragma unroll
  for (int d = 32; d > 0; d >>= 1) m = fmaxf(m, __shfl_xor(m, d));
  float scale = fmaxf(m / 448.0f, 1e-12f);
  unsigned short q0 = f2bf(qd_e4m3(xv.x / scale));  // exact: e4m3 ⊂ bf16
  unsigned short q1 = f2bf(qd_e4m3(xv.y / scale));
  *reinterpret_cast<unsigned*>(q + off) = (unsigned)q0 | ((unsigned)q1 << 16);
  if (lane == 0) s[wid] = scale;
}

// ---------------------------------------------------------------------------
// Weight quant + dequant + hi/lo split + TRANSPOSE: W[K,N] -> WTh/WTl[N,K].
// ---------------------------------------------------------------------------
__global__ __launch_bounds__(256) void quant_w_t(const float* __restrict__ W,
                                                 unsigned short* __restrict__ WTh,
                                                 unsigned short* __restrict__ WTl,
                                                 int K, int N) {
  __shared__ __align__(16) unsigned short Ht[128][72];
  __shared__ __align__(16) unsigned short Lt[128][72];
  const int tid = threadIdx.x;
  const int w = tid >> 6, l = tid & 63;
  const int k0 = blockIdx.y * 64, n0 = blockIdx.x * 128;
#pragma unroll 4
  for (int i = 0; i < 16; ++i) {
    int kl = w * 16 + i;
    float2 xv = *reinterpret_cast<const float2*>(&W[(size_t)(k0 + kl) * N + n0 + l * 2]);
    float m = fmaxf(fabsf(xv.x), fabsf(xv.y));
#pragma unroll
    for (int d = 32; d > 0; d >>= 1) m = fmaxf(m, __shfl_xor(m, d));
    float scale = fmaxf(m / 448.0f, 1e-12f);
    float d0 = qd_e4m3(xv.x / scale) * scale;
    float d1 = qd_e4m3(xv.y / scale) * scale;
    unsigned short h0 = f2bf(d0), h1 = f2bf(d1);
    Ht[l * 2][kl] = h0;
    Ht[l * 2 + 1][kl] = h1;
    Lt[l * 2][kl] = f2bf(d0 - bf2f(h0));
    Lt[l * 2 + 1][kl] = f2bf(d1 - bf2f(h1));
  }
  __syncthreads();
  const int arr = tid >> 7, n = tid & 127;
  const unsigned short(*T)[72] = arr ? Lt : Ht;
  unsigned short* dst = (arr ? WTl : WTh) + (size_t)(n0 + n) * K + k0;
#pragma unroll
  for (int j = 0; j < 8; ++j)
    *reinterpret_cast<bfrag*>(dst + j * 8) = *reinterpret_cast<const bfrag*>(&T[n][j * 8]);
}

// ---------------------------------------------------------------------------
// Quantization-aware MFMA GEMM (round-10 version: global_load_lds w=16 with
// both-sides XOR swizzle — measured win, unchanged).
// ---------------------------------------------------------------------------
template <bool SPLIT>
__global__ __launch_bounds__(256, 2) void gemm_q(const unsigned short* __restrict__ Aq,
                                                 const float* __restrict__ As,
                                                 const unsigned short* __restrict__ WTh,
                                                 const unsigned short* __restrict__ WTl,
                                                 const float* __restrict__ bias,
                                                 float* __restrict__ Cf,
                                                 unsigned short* __restrict__ Ch,
                                                 unsigned short* __restrict__ Cl,
                                                 int M, int N, int K) {
  __shared__ __align__(16) unsigned short Al[128][64];
  __shared__ __align__(16) unsigned short Bh[128][64];
  __shared__ __align__(16) unsigned short Bl[128][64];
  __shared__ float Ss[128][8];
  const int tid = threadIdx.x;
  const int w = tid >> 6, l = tid & 63;
  const int lr = l & 15, lg = l >> 4;
  const int nbx = N >> 7;
  const int nwg = nbx * (M >> 7);
  const int q8 = nwg >> 3;
  const int swz = ((int)blockIdx.x & 7) * q8 + ((int)blockIdx.x >> 3);
  const int row0 = (swz / nbx) << 7, col0 = (swz % nbx) << 7;
  const int wr = (w >> 1) * 64, wc = (w & 1) * 64;
  const int xsw = (lr & 7) * 8;        // read-side XOR (short units)

  {
    int r = tid >> 1, c0 = (tid & 1) * 4;
    *reinterpret_cast<float4*>(&Ss[r][c0]) =
        *reinterpret_cast<const float4*>(&As[(size_t)(row0 + r) * 8 + c0]);
  }

  f4 acc[4][4], seg[4][4];
#pragma unroll
  for (int i = 0; i < 4; ++i)
#pragma unroll
    for (int j = 0; j < 4; ++j)
#pragma unroll
      for (int c = 0; c < 4; ++c) {
        acc[i][j][c] = 0.f;
        seg[i][j][c] = 0.f;
      }

  const int lrow = l >> 3;             // 0..7
  const int jch = (l & 7) ^ lrow;      // inverse-swizzled source chunk
  const unsigned short* pA = Aq + (size_t)(row0 + w * 32 + lrow) * K + jch * 8;
  const unsigned short* pH = WTh + (size_t)(col0 + w * 32 + lrow) * K + jch * 8;
  const unsigned short* pL = WTl + (size_t)(col0 + w * 32 + lrow) * K + jch * 8;
  unsigned short* dA = &Al[0][0] + w * 2048;
  unsigned short* dH = &Bh[0][0] + w * 2048;
  unsigned short* dL = &Bl[0][0] + w * 2048;

  const int niter = K >> 6;
  for (int it = 0; it < niter; ++it) {
    const int k0 = it << 6;
    __syncthreads();
#pragma unroll
    for (int ii = 0; ii < 4; ++ii) {
      gl16(pA + (size_t)ii * 8 * K + k0, dA + ii * 512);
      gl16(pH + (size_t)ii * 8 * K + k0, dH + ii * 512);
      gl16(pL + (size_t)ii * 8 * K + k0, dL + ii * 512);
    }
    __syncthreads();

#pragma unroll
    for (int ks = 0; ks < 2; ++ks) {
      bfrag af[4];
#pragma unroll
      for (int mf = 0; mf < 4; ++mf)
        af[mf] = *reinterpret_cast<const bfrag*>(
            &Al[0][0] + (wr + mf * 16 + lr) * 64 + ((ks * 32 + lg * 8) ^ xsw));
#pragma unroll
      for (int nf = 0; nf < 4; ++nf) {
        bfrag bh = *reinterpret_cast<const bfrag*>(
            &Bh[0][0] + (wc + nf * 16 + lr) * 64 + ((ks * 32 + lg * 8) ^ xsw));
        bfrag bl = *reinterpret_cast<const bfrag*>(
            &Bl[0][0] + (wc + nf * 16 + lr) * 64 + ((ks * 32 + lg * 8) ^ xsw));
#pragma unroll
        for (int mf = 0; mf < 4; ++mf) {
          seg[mf][nf] = MFMA16(af[mf], bh, seg[mf][nf]);
          seg[mf][nf] = MFMA16(af[mf], bl, seg[mf][nf]);
        }
      }
    }

    if (it & 1) {
      const int kb = it >> 1;
#pragma unroll
      for (int mf = 0; mf < 4; ++mf) {
        float sv[4];
#pragma unroll
        for (int r = 0; r < 4; ++r) sv[r] = Ss[wr + mf * 16 + lg * 4 + r][kb];
#pragma unroll
        for (int nf = 0; nf < 4; ++nf)
#pragma unroll
          for (int r = 0; r < 4; ++r) {
            acc[mf][nf][r] += sv[r] * seg[mf][nf][r];
            seg[mf][nf][r] = 0.f;
          }
      }
    }
  }

#pragma unroll
  for (int mf = 0; mf < 4; ++mf) {
#pragma unroll
    for (int r = 0; r < 4; ++r) {
      const int m = row0 + wr + mf * 16 + lg * 4 + r;
#pragma unroll
      for (int nf = 0; nf < 4; ++nf) {
        const int col = col0 + wc + nf * 16 + lr;
        float o = acc[mf][nf][r] + bias[col];
        if (SPLIT) {
          unsigned short hh = f2bf(o);
          Ch[(size_t)m * N + col] = hh;
          Cl[(size_t)m * N + col] = f2bf(o - bf2f(hh));
        } else {
          Cf[(size_t)m * N + col] = o;
        }
      }
    }
  }
}

// ---------------------------------------------------------------------------
// Swapped-operand 32x32 MFMA flash attention, split-bf16 3-pass, KV-SPLIT x2.
// Round-13: cross the 128-reg occupancy boundary (m69: waves/SIMD steps at
// total regs 64/128/256). r12 lean = 84 arch + 48 acc = 132 -> 256-slot ->
// 2 waves/SIMD. Changes: (a) 32-bit offset addressing (uniform SGPR base +
// one unsigned voffset per K/V stream; max offset 12.6M < 2^31) to drop the
// 64-bit per-lane pointer pairs; (b) __launch_bounds__(256,4) pins total
// <= 128 -> 4 waves/SIMD. Grid 1024 blocks = 4 blocks/CU matches.
// Spill watch: FETCH_SIZE must stay ~146 MB.
// ---------------------------------------------------------------------------
__global__ __launch_bounds__(256, 4) void attn_mfma32(const unsigned short* __restrict__ qkvh,
                                                      const unsigned short* __restrict__ qkvl,
                                                      float* __restrict__ O0,
                                                      float* __restrict__ O1,
                                                      float2* __restrict__ ml) {
  __shared__ __align__(16) unsigned short Vth[2][64][40];  // V^T: [buf][rho(d)][kpos]
  __shared__ __align__(16) unsigned short Vtl[2][64][40];
  const int tid = threadIdx.x;
  const int w = tid >> 6, l = tid & 63;
  const int q = l & 31;
  const int hi = l >> 5;
  const int q0 = blockIdx.x * 128 + w * 32;
  const int b = blockIdx.y >> 4, h = blockIdx.y & 15;
  const int half = blockIdx.z;
  const size_t bbase = (size_t)b * 2048;
  const unsigned kvbase = (unsigned)(bbase + half * 1024);
  const unsigned hoff = (unsigned)h * 64;

  const int rA = (q & 24) | ((q + (q >> 3)) & 7);              // d = q
  const int rB = 32 + ((q & 24) | ((q + 4 + (q >> 3)) & 7));   // d = 32+q

  bfrag qh[4], ql[4];
  {
    const unsigned qrow = (unsigned)(bbase + q0 + q) * 3072u + hoff + hi * 8;
#pragma unroll
    for (int f = 0; f < 4; ++f) {
      qh[f] = *reinterpret_cast<const bfrag*>(qkvh + qrow + f * 16);
      ql[f] = *reinterpret_cast<const bfrag*>(qkvl + qrow + f * 16);
    }
  }

  const int skp = tid >> 3;   // 0..31 (kpos)
  const int sc = tid & 7;     // 0..7  (d-chunk of 8)

  // 32-bit element offsets (shared across hi/lo streams; uniform step)
  const unsigned KSTEP_E = 32u * 3072u;
  unsigned ko = (kvbase + q) * 3072u + 1024u + hoff + hi * 8;
  unsigned vo = (kvbase + skp) * 3072u + 2048u + hoff + sc * 8;

  bfrag kh[4], kl[4], svh, svl;

  // ---- prologue: K(0), V(0)->LDS0 ----
#pragma unroll
  for (int f = 0; f < 4; ++f) {
    kh[f] = *reinterpret_cast<const bfrag*>(qkvh + ko + f * 16);
    kl[f] = *reinterpret_cast<const bfrag*>(qkvl + ko + f * 16);
  }
  svh = *reinterpret_cast<const bfrag*>(qkvh + vo);
  svl = *reinterpret_cast<const bfrag*>(qkvl + vo);
  vo += KSTEP_E;
#pragma unroll
  for (int j = 0; j < 8; ++j) {  // static element j -> row rho(sc*8+j)
    int row = sc * 8 + ((j + sc) & 7);
    Vth[0][row][skp] = (unsigned short)svh[j];
    Vtl[0][row][skp] = (unsigned short)svl[j];
  }
  __syncthreads();

  f16v oacc0, oacc1;
#pragma unroll
  for (int r = 0; r < 16; ++r) { oacc0[r] = 0.f; oacc1[r] = 0.f; }
  float m_i = -1e30f, l_i = 0.f;

  for (int kt = 0; kt < 32; ++kt) {
    const int cur = kt & 1;

    // 1: QK(kt) into S (kh/kl prefetched last iter / prologue)
    f16v S;
#pragma unroll
    for (int r = 0; r < 16; ++r) S[r] = 0.f;
    __builtin_amdgcn_s_setprio(1);
#pragma unroll
    for (int f = 0; f < 4; ++f) S = MFMA32(kh[f], qh[f], S);
#pragma unroll
    for (int f = 0; f < 4; ++f) S = MFMA32(kh[f], ql[f], S);
#pragma unroll
    for (int f = 0; f < 4; ++f) S = MFMA32(kl[f], qh[f], S);
    __builtin_amdgcn_s_setprio(0);

    // 2: prefetch K(kt+1)
    if (kt < 31) {
      ko += KSTEP_E;
#pragma unroll
      for (int f = 0; f < 4; ++f) {
        kh[f] = *reinterpret_cast<const bfrag*>(qkvh + ko + f * 16);
        kl[f] = *reinterpret_cast<const bfrag*>(qkvl + ko + f * 16);
      }
    }

    // 3: softmax on S (defer-max THR=0, bit-exact)
    float a0 = fmaxf(S[0], S[1]), a1 = fmaxf(S[2], S[3]);
    float a2 = fmaxf(S[4], S[5]), a3 = fmaxf(S[6], S[7]);
    float a4 = fmaxf(S[8], S[9]), a5 = fmaxf(S[10], S[11]);
    float a6 = fmaxf(S[12], S[13]), a7 = fmaxf(S[14], S[15]);
    float b0_ = fmaxf(a0, a1), b1_ = fmaxf(a2, a3);
    float b2_ = fmaxf(a4, a5), b3_ = fmaxf(a6, a7);
    float mt = fmaxf(fmaxf(b0_, b1_), fmaxf(b2_, b3_));
    mt = fmaxf(mt, __shfl_xor(mt, 32));
    mt *= 0.125f;
    if (!__all(mt <= m_i)) {
      float mn = fmaxf(m_i, mt);
      float corr = __expf(m_i - mn);
      m_i = mn;
      l_i *= corr;
#pragma unroll
      for (int r = 0; r < 16; ++r) { oacc0[r] *= corr; oacc1[r] *= corr; }
    }
    float p[16];
#pragma unroll
    for (int r = 0; r < 16; ++r) p[r] = __expf(fmaf(S[r], 0.125f, -m_i));
    float r0_ = (p[0] + p[1]) + (p[2] + p[3]);
    float r1_ = (p[4] + p[5]) + (p[6] + p[7]);
    float r2_ = (p[8] + p[9]) + (p[10] + p[11]);
    float r3_ = (p[12] + p[13]) + (p[14] + p[15]);
    float rs = (r0_ + r1_) + (r2_ + r3_);
    rs += __shfl_xor(rs, 32);
    l_i += rs;

    // 4: issue V(kt+1) load (written to LDS at step 7)
    if (kt < 31) {
      svh = *reinterpret_cast<const bfrag*>(qkvh + vo);
      svl = *reinterpret_cast<const bfrag*>(qkvl + vo);
      vo += KSTEP_E;
    }

    // 5: pack P hi/lo + permlane32_swap frag build
    unsigned ph_[8], pl_[8];
#pragma unroll
    for (int i = 0; i < 8; ++i) {
      unsigned hp = cvt_pk_bf16(p[2 * i], p[2 * i + 1]);
      float e0 = p[2 * i] - __uint_as_float(hp << 16);
      float e1 = p[2 * i + 1] - __uint_as_float(hp & 0xffff0000u);
      ph_[i] = hp;
      pl_[i] = cvt_pk_bf16(e0, e1);
    }
    permswap(ph_[0], ph_[2]); permswap(ph_[1], ph_[3]);
    permswap(ph_[4], ph_[6]); permswap(ph_[5], ph_[7]);
    permswap(pl_[0], pl_[2]); permswap(pl_[1], pl_[3]);
    permswap(pl_[4], pl_[6]); permswap(pl_[5], pl_[7]);
    union U4 { unsigned u[4]; bfrag f; };
    U4 f0h, f1h, f0l, f1l;
    f0h.u[0] = ph_[0]; f0h.u[1] = ph_[1]; f0h.u[2] = ph_[2]; f0h.u[3] = ph_[3];
    f1h.u[0] = ph_[4]; f1h.u[1] = ph_[5]; f1h.u[2] = ph_[6]; f1h.u[3] = ph_[7];
    f0l.u[0] = pl_[0]; f0l.u[1] = pl_[1]; f0l.u[2] = pl_[2]; f0l.u[3] = pl_[3];
    f1l.u[0] = pl_[4]; f1l.u[1] = pl_[5]; f1l.u[2] = pl_[6]; f1l.u[3] = pl_[7];

    // 6: PV(kt) from LDS[cur], rho rows; 2 interleaved accumulator chains
    __builtin_amdgcn_s_setprio(1);
#pragma unroll
    for (int c = 0; c < 2; ++c) {
      bfrag pF = c ? f1h.f : f0h.f;
      bfrag pL = c ? f1l.f : f0l.f;
      bfrag vh0 = *reinterpret_cast<const bfrag*>(&Vth[cur][rA][c * 16 + hi * 8]);
      bfrag vl0 = *reinterpret_cast<const bfrag*>(&Vtl[cur][rA][c * 16 + hi * 8]);
      bfrag vh1 = *reinterpret_cast<const bfrag*>(&Vth[cur][rB][c * 16 + hi * 8]);
      bfrag vl1 = *reinterpret_cast<const bfrag*>(&Vtl[cur][rB][c * 16 + hi * 8]);
      oacc0 = MFMA32(vh0, pF, oacc0);
      oacc1 = MFMA32(vh1, pF, oacc1);
      oacc0 = MFMA32(vh0, pL, oacc0);
      oacc1 = MFMA32(vh1, pL, oacc1);
      oacc0 = MFMA32(vl0, pF, oacc0);
      oacc1 = MFMA32(vl1, pF, oacc1);
    }
    __builtin_amdgcn_s_setprio(0);

    // 7: write staged V(kt+1) (static element, rho rows), barrier
    if (kt < 31) {
#pragma unroll
      for (int j = 0; j < 8; ++j) {
        int row = sc * 8 + ((j + sc) & 7);
        Vth[cur ^ 1][row][skp] = (unsigned short)svh[j];
        Vtl[cur ^ 1][row][skp] = (unsigned short)svl[j];
      }
      __syncthreads();
    }
  }

  // ---- epilogue: UNNORMALIZED partial store + (m_i, l_i) ----
  float* dst = half ? O1 : O0;
  const size_t row = bbase + q0 + q;
  const size_t orow = row * 1024 + hoff;
#pragma unroll
  for (int dblk = 0; dblk < 2; ++dblk) {
#pragma unroll
    for (int rg = 0; rg < 4; ++rg) {
      float4 o;
      if (dblk == 0) {
        o.x = oacc0[rg * 4 + 0]; o.y = oacc0[rg * 4 + 1];
        o.z = oacc0[rg * 4 + 2]; o.w = oacc0[rg * 4 + 3];
      } else {
        o.x = oacc1[rg * 4 + 0]; o.y = oacc1[rg * 4 + 1];
        o.z = oacc1[rg * 4 + 2]; o.w = oacc1[rg * 4 + 3];
      }
      *reinterpret_cast<float4*>(dst + orow + dblk * 32 + rg * 8 + hi * 4) = o;
    }
  }
  if (hi == 0) ml[(size_t)half * (4096 * 16) + row * 16 + h] = make_float2(m_i, l_i);
}

// ---------------------------------------------------------------------------
// Combine the two KV-half partials (m in natural-log domain -> __expf).
// 1 thread = 1 float4; 4096 rows x 256 float4/row; in-place on O0.
// ---------------------------------------------------------------------------
__global__ __launch_bounds__(256) void attn_combine(float* __restrict__ O0,
                                                    const float* __restrict__ O1,
                                                    const float2* __restrict__ ml) {
  int gid = blockIdx.x * 256 + threadIdx.x;
  int row = gid >> 8;          // 256 float4 per row
  int h = (gid & 255) >> 4;    // 16 float4 per head
  float2 ml0 = ml[(size_t)row * 16 + h];
  float2 ml1 = ml[(size_t)(4096 * 16) + (size_t)row * 16 + h];
  float m = fmaxf(ml0.x, ml1.x);
  float a0 = __expf(ml0.x - m), a1 = __expf(ml1.x - m);
  float inv = 1.0f / fmaf(ml0.y, a0, ml1.y * a1);
  float4 o0 = reinterpret_cast<const float4*>(O0)[gid];
  float4 o1 = reinterpret_cast<const float4*>(O1)[gid];
  float4 o;
  o.x = fmaf(o0.x, a0, o1.x * a1) * inv;
  o.y = fmaf(o0.y, a0, o1.y * a1) * inv;
  o.z = fmaf(o0.z, a0, o1.z * a1) * inv;
  o.w = fmaf(o0.w, a0, o1.w * a1) * inv;
  reinterpret_cast<float4*>(O0)[gid] = o;
}

// ---------------------------------------------------------------------------
// Workspace layout (72.25 MiB peak):
//   @ 0        : x_q bf16 (8 MiB)   | during attn: O1 partial [0,16) MiB
//   @ 8 MiB    : s_x (128 KiB)      |   + ml [16,17) MiB (x_q/s_x/wq* dead)
//   @ 8.25 MiB : WTqkv_h (6 MiB)    @ 14.25 : WTqkv_l (6 MiB)
//   @ 20.25    : WTout_h (2 MiB)    @ 22.25 : WTout_l (2 MiB)
//   @ 24.25    : qkvh (24 MiB)      @ 48.25 : qkvl (24 MiB)
// ---------------------------------------------------------------------------
extern "C" void kernel_launch(void* const* d_in, const int* in_sizes, int n_in,
                              void* d_out, int out_size, void* d_ws, size_t ws_size,
                              hipStream_t stream) {
  const float* x     = (const float*)d_in[0];
  const float* W_qkv = (const float*)d_in[1];
  const float* b_qkv = (const float*)d_in[2];
  const float* W_out = (const float*)d_in[3];
  const float* b_out = (const float*)d_in[4];
  float* y = (float*)d_out;

  char* ws = (char*)d_ws;
  const size_t MB = 1u << 20;
  unsigned short* x_q   = (unsigned short*)(ws);
  float*          s_x   = (float*)(ws + 8 * MB);
  unsigned short* wqh   = (unsigned short*)(ws + 8 * MB + 256 * 1024);
  unsigned short* wql   = (unsigned short*)(ws + 14 * MB + 256 * 1024);
  unsigned short* woh   = (unsigned short*)(ws + 20 * MB + 256 * 1024);
  unsigned short* wol   = (unsigned short*)(ws + 22 * MB + 256 * 1024);
  unsigned short* qkvh  = (unsigned short*)(ws + 24 * MB + 256 * 1024);
  unsigned short* qkvl  = (unsigned short*)(ws + 48 * MB + 256 * 1024);
  float*          O1    = (float*)(ws);             // attn-phase alias (dead x_q/wq*)
  float2*         ml    = (float2*)(ws + 16 * MB);  // [2][4096][16]

  // 1. quantize activations (codes + scales) and weights (split + transpose)
  quant_x<<<8192, 256, 0, stream>>>(x, x_q, s_x, 32768);
  quant_w_t<<<dim3(24, 16), 256, 0, stream>>>(W_qkv, wqh, wql, 1024, 3072);
  quant_w_t<<<dim3(8, 16), 256, 0, stream>>>(W_out, woh, wol, 1024, 1024);

  // 2. QKV projection (quant-aware MFMA, gload_lds staging) -> split bf16
  gemm_q<true><<<768, 256, 0, stream>>>(x_q, s_x, wqh, wql, b_qkv,
                                        nullptr, qkvh, qkvl, 4096, 3072, 1024);

  // 3. 4-wave/SIMD lean KV-split flash attention (2 halves) + combine
  attn_mfma32<<<dim3(16, 32, 2), 256, 0, stream>>>(qkvh, qkvl, y, O1, ml);
  attn_combine<<<4096, 256, 0, stream>>>(y, O1, ml);

  // 4. quantize attention output (reuse x_q / s_x buffers)
  quant_x<<<8192, 256, 0, stream>>>(y, x_q, s_x, 32768);

  // 5. output projection (quant-aware MFMA) -> fp32 d_out
  gemm_q<false><<<256, 256, 0, stream>>>(x_q, s_x, woh, wol, b_out,
                                         y, nullptr, nullptr, 4096, 1024, 1024);
}

// Round 14
// 283.565 us; speedup vs baseline: 1.3523x; 1.3523x over previous
//
#include <hip/hip_runtime.h>
#include <cstdint>
#include <cstddef>

typedef __attribute__((ext_vector_type(8))) short bfrag;    // 8 bf16 (4 VGPR)
typedef __attribute__((ext_vector_type(4))) float f4;       // 16x16 MFMA C/D
typedef __attribute__((ext_vector_type(16))) float f16v;    // 32x32 MFMA C/D

#define MFMA16(a, b, c) __builtin_amdgcn_mfma_f32_16x16x32_bf16(a, b, c, 0, 0, 0)
#define MFMA32(a, b, c) __builtin_amdgcn_mfma_f32_32x32x16_bf16(a, b, c, 0, 0, 0)

// ---------------------------------------------------------------------------
// fp32 -> bf16 RNE, and hi/lo split helpers
// ---------------------------------------------------------------------------
__device__ __forceinline__ unsigned short f2bf(float x) {
  unsigned u = __float_as_uint(x);
  u += 0x7fffu + ((u >> 16) & 1u);
  return (unsigned short)(u >> 16);
}
__device__ __forceinline__ float bf2f(unsigned short h) {
  return __uint_as_float(((unsigned)h) << 16);
}
// HW packed f32->2xbf16 (one instr). Rounding-mode-agnostic use: the lo
// residue compensates whatever hi rounds to.
__device__ __forceinline__ unsigned cvt_pk_bf16(float a, float b) {
  unsigned r;
  asm("v_cvt_pk_bf16_f32 %0, %1, %2" : "=v"(r) : "v"(a), "v"(b));
  return r;
}
// One-instruction cross-half exchange: a' = [a_lo | b_lo], b' = [a_hi | b_hi].
__device__ __forceinline__ void permswap(unsigned& a, unsigned& b) {
  auto r = __builtin_amdgcn_permlane32_swap((int)a, (int)b, false, false);
  a = (unsigned)r[0];
  b = (unsigned)r[1];
}
// Async global->LDS, 16B per lane. Dest is wave-uniform base + lane*16.
__device__ __forceinline__ void gl16(const unsigned short* g, unsigned short* l) {
  __builtin_amdgcn_global_load_lds(
      (const __attribute__((address_space(1))) unsigned int*)g,
      (__attribute__((address_space(3))) unsigned int*)l, 16, 0, 0);
}

// ---------------------------------------------------------------------------
// Software-exact OCP e4m3fn rounding (RTNE via magic-add; matches ml_dtypes
// bit-exact incl. subnormal grid 2^-9 and the 448-saturation region).
// ---------------------------------------------------------------------------
__device__ __forceinline__ float qd_e4m3(float v) {
  float a = fabsf(v);
  unsigned u = __float_as_uint(a);
  int e = (int)(u >> 23) - 127;
  int k = e - 3;
  if (k < -9) k = -9;
  float big = __uint_as_float((unsigned)(k + 150) << 23);  // 2^(k+23)
  float r = (a + big) - big;
  return __builtin_copysignf(r, v);
}

// ---------------------------------------------------------------------------
// Activation quant: per 128-block, emit e4m3 CODES as bf16 (exact) + scale.
// ---------------------------------------------------------------------------
__global__ __launch_bounds__(256) void quant_x(const float* __restrict__ src,
                                               unsigned short* __restrict__ q,
                                               float* __restrict__ s,
                                               int nblk) {
  int gid = blockIdx.x * 256 + threadIdx.x;
  int wid = gid >> 6;
  int lane = gid & 63;
  if (wid >= nblk) return;
  size_t off = (size_t)wid * 128 + lane * 2;
  float2 xv = *reinterpret_cast<const float2*>(src + off);
  float m = fmaxf(fabsf(xv.x), fabsf(xv.y));
#pragma unroll
  for (int d = 32; d > 0; d >>= 1) m = fmaxf(m, __shfl_xor(m, d));
  float scale = fmaxf(m / 448.0f, 1e-12f);
  unsigned short q0 = f2bf(qd_e4m3(xv.x / scale));  // exact: e4m3 ⊂ bf16
  unsigned short q1 = f2bf(qd_e4m3(xv.y / scale));
  *reinterpret_cast<unsigned*>(q + off) = (unsigned)q0 | ((unsigned)q1 << 16);
  if (lane == 0) s[wid] = scale;
}

// ---------------------------------------------------------------------------
// Weight quant + dequant + hi/lo split + TRANSPOSE: W[K,N] -> WTh/WTl[N,K].
// ---------------------------------------------------------------------------
__global__ __launch_bounds__(256) void quant_w_t(const float* __restrict__ W,
                                                 unsigned short* __restrict__ WTh,
                                                 unsigned short* __restrict__ WTl,
                                                 int K, int N) {
  __shared__ __align__(16) unsigned short Ht[128][72];
  __shared__ __align__(16) unsigned short Lt[128][72];
  const int tid = threadIdx.x;
  const int w = tid >> 6, l = tid & 63;
  const int k0 = blockIdx.y * 64, n0 = blockIdx.x * 128;
#pragma unroll 4
  for (int i = 0; i < 16; ++i) {
    int kl = w * 16 + i;
    float2 xv = *reinterpret_cast<const float2*>(&W[(size_t)(k0 + kl) * N + n0 + l * 2]);
    float m = fmaxf(fabsf(xv.x), fabsf(xv.y));
#pragma unroll
    for (int d = 32; d > 0; d >>= 1) m = fmaxf(m, __shfl_xor(m, d));
    float scale = fmaxf(m / 448.0f, 1e-12f);
    float d0 = qd_e4m3(xv.x / scale) * scale;
    float d1 = qd_e4m3(xv.y / scale) * scale;
    unsigned short h0 = f2bf(d0), h1 = f2bf(d1);
    Ht[l * 2][kl] = h0;
    Ht[l * 2 + 1][kl] = h1;
    Lt[l * 2][kl] = f2bf(d0 - bf2f(h0));
    Lt[l * 2 + 1][kl] = f2bf(d1 - bf2f(h1));
  }
  __syncthreads();
  const int arr = tid >> 7, n = tid & 127;
  const unsigned short(*T)[72] = arr ? Lt : Ht;
  unsigned short* dst = (arr ? WTl : WTh) + (size_t)(n0 + n) * K + k0;
#pragma unroll
  for (int j = 0; j < 8; ++j)
    *reinterpret_cast<bfrag*>(dst + j * 8) = *reinterpret_cast<const bfrag*>(&T[n][j * 8]);
}

// ---------------------------------------------------------------------------
// Quantization-aware MFMA GEMM (round-10 version: global_load_lds w=16 with
// both-sides XOR swizzle — measured win, unchanged).
// ---------------------------------------------------------------------------
template <bool SPLIT>
__global__ __launch_bounds__(256, 2) void gemm_q(const unsigned short* __restrict__ Aq,
                                                 const float* __restrict__ As,
                                                 const unsigned short* __restrict__ WTh,
                                                 const unsigned short* __restrict__ WTl,
                                                 const float* __restrict__ bias,
                                                 float* __restrict__ Cf,
                                                 unsigned short* __restrict__ Ch,
                                                 unsigned short* __restrict__ Cl,
                                                 int M, int N, int K) {
  __shared__ __align__(16) unsigned short Al[128][64];
  __shared__ __align__(16) unsigned short Bh[128][64];
  __shared__ __align__(16) unsigned short Bl[128][64];
  __shared__ float Ss[128][8];
  const int tid = threadIdx.x;
  const int w = tid >> 6, l = tid & 63;
  const int lr = l & 15, lg = l >> 4;
  const int nbx = N >> 7;
  const int nwg = nbx * (M >> 7);
  const int q8 = nwg >> 3;
  const int swz = ((int)blockIdx.x & 7) * q8 + ((int)blockIdx.x >> 3);
  const int row0 = (swz / nbx) << 7, col0 = (swz % nbx) << 7;
  const int wr = (w >> 1) * 64, wc = (w & 1) * 64;
  const int xsw = (lr & 7) * 8;        // read-side XOR (short units)

  {
    int r = tid >> 1, c0 = (tid & 1) * 4;
    *reinterpret_cast<float4*>(&Ss[r][c0]) =
        *reinterpret_cast<const float4*>(&As[(size_t)(row0 + r) * 8 + c0]);
  }

  f4 acc[4][4], seg[4][4];
#pragma unroll
  for (int i = 0; i < 4; ++i)
#pragma unroll
    for (int j = 0; j < 4; ++j)
#pragma unroll
      for (int c = 0; c < 4; ++c) {
        acc[i][j][c] = 0.f;
        seg[i][j][c] = 0.f;
      }

  const int lrow = l >> 3;             // 0..7
  const int jch = (l & 7) ^ lrow;      // inverse-swizzled source chunk
  const unsigned short* pA = Aq + (size_t)(row0 + w * 32 + lrow) * K + jch * 8;
  const unsigned short* pH = WTh + (size_t)(col0 + w * 32 + lrow) * K + jch * 8;
  const unsigned short* pL = WTl + (size_t)(col0 + w * 32 + lrow) * K + jch * 8;
  unsigned short* dA = &Al[0][0] + w * 2048;
  unsigned short* dH = &Bh[0][0] + w * 2048;
  unsigned short* dL = &Bl[0][0] + w * 2048;

  const int niter = K >> 6;
  for (int it = 0; it < niter; ++it) {
    const int k0 = it << 6;
    __syncthreads();
#pragma unroll
    for (int ii = 0; ii < 4; ++ii) {
      gl16(pA + (size_t)ii * 8 * K + k0, dA + ii * 512);
      gl16(pH + (size_t)ii * 8 * K + k0, dH + ii * 512);
      gl16(pL + (size_t)ii * 8 * K + k0, dL + ii * 512);
    }
    __syncthreads();

#pragma unroll
    for (int ks = 0; ks < 2; ++ks) {
      bfrag af[4];
#pragma unroll
      for (int mf = 0; mf < 4; ++mf)
        af[mf] = *reinterpret_cast<const bfrag*>(
            &Al[0][0] + (wr + mf * 16 + lr) * 64 + ((ks * 32 + lg * 8) ^ xsw));
#pragma unroll
      for (int nf = 0; nf < 4; ++nf) {
        bfrag bh = *reinterpret_cast<const bfrag*>(
            &Bh[0][0] + (wc + nf * 16 + lr) * 64 + ((ks * 32 + lg * 8) ^ xsw));
        bfrag bl = *reinterpret_cast<const bfrag*>(
            &Bl[0][0] + (wc + nf * 16 + lr) * 64 + ((ks * 32 + lg * 8) ^ xsw));
#pragma unroll
        for (int mf = 0; mf < 4; ++mf) {
          seg[mf][nf] = MFMA16(af[mf], bh, seg[mf][nf]);
          seg[mf][nf] = MFMA16(af[mf], bl, seg[mf][nf]);
        }
      }
    }

    if (it & 1) {
      const int kb = it >> 1;
#pragma unroll
      for (int mf = 0; mf < 4; ++mf) {
        float sv[4];
#pragma unroll
        for (int r = 0; r < 4; ++r) sv[r] = Ss[wr + mf * 16 + lg * 4 + r][kb];
#pragma unroll
        for (int nf = 0; nf < 4; ++nf)
#pragma unroll
          for (int r = 0; r < 4; ++r) {
            acc[mf][nf][r] += sv[r] * seg[mf][nf][r];
            seg[mf][nf][r] = 0.f;
          }
      }
    }
  }

#pragma unroll
  for (int mf = 0; mf < 4; ++mf) {
#pragma unroll
    for (int r = 0; r < 4; ++r) {
      const int m = row0 + wr + mf * 16 + lg * 4 + r;
#pragma unroll
      for (int nf = 0; nf < 4; ++nf) {
        const int col = col0 + wc + nf * 16 + lr;
        float o = acc[mf][nf][r] + bias[col];
        if (SPLIT) {
          unsigned short hh = f2bf(o);
          Ch[(size_t)m * N + col] = hh;
          Cl[(size_t)m * N + col] = f2bf(o - bf2f(hh));
        } else {
          Cf[(size_t)m * N + col] = o;
        }
      }
    }
  }
}

// ---------------------------------------------------------------------------
// Swapped-operand 32x32 MFMA flash attention (round-7/10 body, measured 172us
// best) + round-14 XCD-AWARE GRID REMAP: 1-D grid 512; XCD k (= lin%8) owns
// bh in {4k..4k+3} entirely, so each XCD's L2 streams only 4 KV sequences
// (4 MiB fits L2) instead of 32 (thrash -> L3 latency on K loads).
// Decode: xcd=lin&7, j=lin>>3, bh=4*xcd+(j>>4), qt=j&15. Bijective.
// ---------------------------------------------------------------------------
__global__ __launch_bounds__(256, 2) void attn_mfma32(const unsigned short* __restrict__ qkvh,
                                                      const unsigned short* __restrict__ qkvl,
                                                      float* __restrict__ out) {
  __shared__ __align__(16) unsigned short Vth[2][64][40];  // V^T: [buf][rho(d)][kpos]
  __shared__ __align__(16) unsigned short Vtl[2][64][40];
  const int tid = threadIdx.x;
  const int w = tid >> 6, l = tid & 63;
  const int q = l & 31;
  const int hi = l >> 5;
  // XCD-aware decode (see header comment)
  const int lin = (int)blockIdx.x;
  const int xcd = lin & 7, j = lin >> 3;
  const int bh = 4 * xcd + (j >> 4);
  const int qt = j & 15;
  const int q0 = qt * 128 + w * 32;
  const int b = bh >> 4, h = bh & 15;
  const size_t bbase = (size_t)b * 2048;
  const size_t hoff = (size_t)h * 64;

  const int rA = (q & 24) | ((q + (q >> 3)) & 7);              // d = q
  const int rB = 32 + ((q & 24) | ((q + 4 + (q >> 3)) & 7));   // d = 32+q

  bfrag qh[4], ql[4];
  {
    const size_t qrow = (bbase + q0 + q) * 3072 + hoff + hi * 8;
#pragma unroll
    for (int f = 0; f < 4; ++f) {
      qh[f] = *reinterpret_cast<const bfrag*>(qkvh + qrow + f * 16);
      ql[f] = *reinterpret_cast<const bfrag*>(qkvl + qrow + f * 16);
    }
  }

  const int skp = tid >> 3;   // 0..31 (kpos)
  const int sc = tid & 7;     // 0..7  (d-chunk of 8)

  const unsigned short* kph = qkvh + (bbase + q) * 3072 + 1024 + hoff + hi * 8;
  const unsigned short* kpl = qkvl + (bbase + q) * 3072 + 1024 + hoff + hi * 8;
  const unsigned short* vph = qkvh + (bbase + skp) * 3072 + 2048 + hoff + sc * 8;
  const unsigned short* vpl = qkvl + (bbase + skp) * 3072 + 2048 + hoff + sc * 8;
  const size_t KSTEP = (size_t)32 * 3072;

  bfrag kh[4], kl[4], svh, svl;

  // ---- prologue: K(0), V(0)->LDS0, QK(0)->sA, K(1) ----
#pragma unroll
  for (int f = 0; f < 4; ++f) {
    kh[f] = *reinterpret_cast<const bfrag*>(kph + f * 16);
    kl[f] = *reinterpret_cast<const bfrag*>(kpl + f * 16);
  }
  svh = *reinterpret_cast<const bfrag*>(vph);
  svl = *reinterpret_cast<const bfrag*>(vpl);
  vph += KSTEP; vpl += KSTEP;
#pragma unroll
  for (int j2 = 0; j2 < 8; ++j2) {  // static element j2 -> row rho(sc*8+j2)
    int row = sc * 8 + ((j2 + sc) & 7);
    Vth[0][row][skp] = (unsigned short)svh[j2];
    Vtl[0][row][skp] = (unsigned short)svl[j2];
  }
  f16v sA, sB;
#pragma unroll
  for (int r = 0; r < 16; ++r) sA[r] = 0.f;
  __builtin_amdgcn_s_setprio(1);
#pragma unroll
  for (int f = 0; f < 4; ++f) sA = MFMA32(kh[f], qh[f], sA);
#pragma unroll
  for (int f = 0; f < 4; ++f) sA = MFMA32(kh[f], ql[f], sA);
#pragma unroll
  for (int f = 0; f < 4; ++f) sA = MFMA32(kl[f], qh[f], sA);
  __builtin_amdgcn_s_setprio(0);
  kph += KSTEP; kpl += KSTEP;
#pragma unroll
  for (int f = 0; f < 4; ++f) {
    kh[f] = *reinterpret_cast<const bfrag*>(kph + f * 16);
    kl[f] = *reinterpret_cast<const bfrag*>(kpl + f * 16);
  }
  __syncthreads();

  f16v oA0, oA1, oB0, oB1;
#pragma unroll
  for (int r = 0; r < 16; ++r) { oA0[r] = 0.f; oA1[r] = 0.f; oB0[r] = 0.f; oB1[r] = 0.f; }
  float m_i = -1e30f, l_i = 0.f;

#define ATTN_ITER(KT, SCUR, SNXT)                                              \
  do {                                                                         \
    const int kt_ = (KT);                                                      \
    const int cur_ = kt_ & 1;                                                  \
    /* 1: issue QK(kt+1) into SNXT (overlaps softmax below) */                 \
    if (kt_ < 63) {                                                            \
      _Pragma("unroll") for (int r = 0; r < 16; ++r) SNXT[r] = 0.f;            \
      __builtin_amdgcn_s_setprio(1);                                           \
      _Pragma("unroll") for (int f = 0; f < 4; ++f)                            \
          SNXT = MFMA32(kh[f], qh[f], SNXT);                                   \
      _Pragma("unroll") for (int f = 0; f < 4; ++f)                            \
          SNXT = MFMA32(kh[f], ql[f], SNXT);                                   \
      _Pragma("unroll") for (int f = 0; f < 4; ++f)                            \
          SNXT = MFMA32(kl[f], qh[f], SNXT);                                   \
      __builtin_amdgcn_s_setprio(0);                                           \
    }                                                                          \
    /* 2: K(kt+2) loads */                                                     \
    if (kt_ < 62) {                                                            \
      kph += KSTEP; kpl += KSTEP;                                              \
      _Pragma("unroll") for (int f = 0; f < 4; ++f) {                          \
        kh[f] = *reinterpret_cast<const bfrag*>(kph + f * 16);                 \
        kl[f] = *reinterpret_cast<const bfrag*>(kpl + f * 16);                 \
      }                                                                        \
    }                                                                          \
    /* 3: softmax on SCUR (VALU — overlaps step-1 MFMAs) */                    \
    float a0 = fmaxf(SCUR[0], SCUR[1]), a1 = fmaxf(SCUR[2], SCUR[3]);          \
    float a2 = fmaxf(SCUR[4], SCUR[5]), a3 = fmaxf(SCUR[6], SCUR[7]);          \
    float a4 = fmaxf(SCUR[8], SCUR[9]), a5 = fmaxf(SCUR[10], SCUR[11]);        \
    float a6 = fmaxf(SCUR[12], SCUR[13]), a7 = fmaxf(SCUR[14], SCUR[15]);      \
    float b0_ = fmaxf(a0, a1), b1_ = fmaxf(a2, a3);                            \
    float b2_ = fmaxf(a4, a5), b3_ = fmaxf(a6, a7);                            \
    float mt = fmaxf(fmaxf(b0_, b1_), fmaxf(b2_, b3_));                        \
    mt = fmaxf(mt, __shfl_xor(mt, 32));                                        \
    mt *= 0.125f;                                                              \
    if (!__all(mt <= m_i)) { /* defer-max: THR=0 is bit-exact */               \
      float mn = fmaxf(m_i, mt);                                               \
      float corr = __expf(m_i - mn);                                           \
      m_i = mn;                                                                \
      l_i *= corr;                                                             \
      _Pragma("unroll") for (int r = 0; r < 16; ++r) {                         \
        oA0[r] *= corr; oA1[r] *= corr; oB0[r] *= corr; oB1[r] *= corr;        \
      }                                                                        \
    }                                                                          \
    float p[16];                                                               \
    _Pragma("unroll") for (int r = 0; r < 16; ++r)                             \
        p[r] = __expf(fmaf(SCUR[r], 0.125f, -m_i));                            \
    float r0_ = (p[0] + p[1]) + (p[2] + p[3]);                                 \
    float r1_ = (p[4] + p[5]) + (p[6] + p[7]);                                 \
    float r2_ = (p[8] + p[9]) + (p[10] + p[11]);                               \
    float r3_ = (p[12] + p[13]) + (p[14] + p[15]);                             \
    float rs = (r0_ + r1_) + (r2_ + r3_);                                      \
    rs += __shfl_xor(rs, 32);                                                  \
    l_i += rs;                                                                 \
    /* 4: issue V(kt+1) load (written to LDS at step 7) */                     \
    if (kt_ < 63) {                                                            \
      svh = *reinterpret_cast<const bfrag*>(vph);                              \
      svl = *reinterpret_cast<const bfrag*>(vpl);                              \
      vph += KSTEP; vpl += KSTEP;                                              \
    }                                                                          \
    /* 5: pack P hi/lo + permlane32_swap frag build */                         \
    unsigned ph_[8], pl_[8];                                                   \
    _Pragma("unroll") for (int i = 0; i < 8; ++i) {                            \
      unsigned hp = cvt_pk_bf16(p[2 * i], p[2 * i + 1]);                       \
      float e0 = p[2 * i] - __uint_as_float(hp << 16);                         \
      float e1 = p[2 * i + 1] - __uint_as_float(hp & 0xffff0000u);             \
      ph_[i] = hp;                                                             \
      pl_[i] = cvt_pk_bf16(e0, e1);                                            \
    }                                                                          \
    permswap(ph_[0], ph_[2]); permswap(ph_[1], ph_[3]);                        \
    permswap(ph_[4], ph_[6]); permswap(ph_[5], ph_[7]);                        \
    permswap(pl_[0], pl_[2]); permswap(pl_[1], pl_[3]);                        \
    permswap(pl_[4], pl_[6]); permswap(pl_[5], pl_[7]);                        \
    union U4 { unsigned u[4]; bfrag f; };                                      \
    U4 f0h, f1h, f0l, f1l;                                                     \
    f0h.u[0] = ph_[0]; f0h.u[1] = ph_[1]; f0h.u[2] = ph_[2]; f0h.u[3] = ph_[3];\
    f1h.u[0] = ph_[4]; f1h.u[1] = ph_[5]; f1h.u[2] = ph_[6]; f1h.u[3] = ph_[7];\
    f0l.u[0] = pl_[0]; f0l.u[1] = pl_[1]; f0l.u[2] = pl_[2]; f0l.u[3] = pl_[3];\
    f1l.u[0] = pl_[4]; f1l.u[1] = pl_[5]; f1l.u[2] = pl_[6]; f1l.u[3] = pl_[7];\
    /* 6: PV(kt) from LDS[cur_], rho rows */                                   \
    __builtin_amdgcn_s_setprio(1);                                             \
    _Pragma("unroll") for (int c = 0; c < 2; ++c) {                            \
      bfrag pF = c ? f1h.f : f0h.f;                                            \
      bfrag pL = c ? f1l.f : f0l.f;                                            \
      bfrag vh0 = *reinterpret_cast<const bfrag*>(&Vth[cur_][rA][c * 16 + hi * 8]); \
      bfrag vl0 = *reinterpret_cast<const bfrag*>(&Vtl[cur_][rA][c * 16 + hi * 8]); \
      bfrag vh1 = *reinterpret_cast<const bfrag*>(&Vth[cur_][rB][c * 16 + hi * 8]); \
      bfrag vl1 = *reinterpret_cast<const bfrag*>(&Vtl[cur_][rB][c * 16 + hi * 8]); \
      oA0 = MFMA32(vh0, pF, oA0);                                              \
      oB0 = MFMA32(vh0, pL, oB0);                                              \
      oB0 = MFMA32(vl0, pF, oB0);                                              \
      oA1 = MFMA32(vh1, pF, oA1);                                              \
      oB1 = MFMA32(vh1, pL, oB1);                                              \
      oB1 = MFMA32(vl1, pF, oB1);                                              \
    }                                                                          \
    __builtin_amdgcn_s_setprio(0);                                             \
    /* 7: write staged V(kt+1) (static element, rho rows), barrier */          \
    if (kt_ < 63) {                                                            \
      _Pragma("unroll") for (int j2 = 0; j2 < 8; ++j2) {                       \
        int row = sc * 8 + ((j2 + sc) & 7);                                    \
        Vth[cur_ ^ 1][row][skp] = (unsigned short)svh[j2];                     \
        Vtl[cur_ ^ 1][row][skp] = (unsigned short)svl[j2];                     \
      }                                                                        \
      __syncthreads();                                                         \
    }                                                                          \
  } while (0)

  for (int kt = 0; kt < 64; kt += 2) {
    ATTN_ITER(kt, sA, sB);
    ATTN_ITER(kt + 1, sB, sA);
  }
#undef ATTN_ITER

  // ---- epilogue: combine chains, normalize, store fp32 [B,S,H*Dh] ----
  float inv = 1.0f / l_i;
  const size_t orow = (bbase + q0 + q) * 1024 + hoff;
#pragma unroll
  for (int dblk = 0; dblk < 2; ++dblk) {
#pragma unroll
    for (int rg = 0; rg < 4; ++rg) {
      float4 o;
      if (dblk == 0) {
        o.x = (oA0[rg * 4 + 0] + oB0[rg * 4 + 0]) * inv;
        o.y = (oA0[rg * 4 + 1] + oB0[rg * 4 + 1]) * inv;
        o.z = (oA0[rg * 4 + 2] + oB0[rg * 4 + 2]) * inv;
        o.w = (oA0[rg * 4 + 3] + oB0[rg * 4 + 3]) * inv;
      } else {
        o.x = (oA1[rg * 4 + 0] + oB1[rg * 4 + 0]) * inv;
        o.y = (oA1[rg * 4 + 1] + oB1[rg * 4 + 1]) * inv;
        o.z = (oA1[rg * 4 + 2] + oB1[rg * 4 + 2]) * inv;
        o.w = (oA1[rg * 4 + 3] + oB1[rg * 4 + 3]) * inv;
      }
      *reinterpret_cast<float4*>(out + orow + dblk * 32 + rg * 8 + hi * 4) = o;
    }
  }
}

// ---------------------------------------------------------------------------
// Workspace layout (72.25 MiB) — unchanged.
// ---------------------------------------------------------------------------
extern "C" void kernel_launch(void* const* d_in, const int* in_sizes, int n_in,
                              void* d_out, int out_size, void* d_ws, size_t ws_size,
                              hipStream_t stream) {
  const float* x     = (const float*)d_in[0];
  const float* W_qkv = (const float*)d_in[1];
  const float* b_qkv = (const float*)d_in[2];
  const float* W_out = (const float*)d_in[3];
  const float* b_out = (const float*)d_in[4];
  float* y = (float*)d_out;

  char* ws = (char*)d_ws;
  const size_t MB = 1u << 20;
  unsigned short* x_q   = (unsigned short*)(ws);
  float*          s_x   = (float*)(ws + 8 * MB);
  unsigned short* wqh   = (unsigned short*)(ws + 8 * MB + 256 * 1024);
  unsigned short* wql   = (unsigned short*)(ws + 14 * MB + 256 * 1024);
  unsigned short* woh   = (unsigned short*)(ws + 20 * MB + 256 * 1024);
  unsigned short* wol   = (unsigned short*)(ws + 22 * MB + 256 * 1024);
  unsigned short* qkvh  = (unsigned short*)(ws + 24 * MB + 256 * 1024);
  unsigned short* qkvl  = (unsigned short*)(ws + 48 * MB + 256 * 1024);

  // 1. quantize activations (codes + scales) and weights (split + transpose)
  quant_x<<<8192, 256, 0, stream>>>(x, x_q, s_x, 32768);
  quant_w_t<<<dim3(24, 16), 256, 0, stream>>>(W_qkv, wqh, wql, 1024, 3072);
  quant_w_t<<<dim3(8, 16), 256, 0, stream>>>(W_out, woh, wol, 1024, 1024);

  // 2. QKV projection (quant-aware MFMA, gload_lds staging) -> split bf16
  gemm_q<true><<<768, 256, 0, stream>>>(x_q, s_x, wqh, wql, b_qkv,
                                        nullptr, qkvh, qkvl, 4096, 3072, 1024);

  // 3. pipelined swapped 32x32 MFMA flash attention (XCD-remapped 1-D grid)
  attn_mfma32<<<512, 256, 0, stream>>>(qkvh, qkvl, y);

  // 4. quantize attention output (reuse x_q / s_x buffers)
  quant_x<<<8192, 256, 0, stream>>>(y, x_q, s_x, 32768);

  // 5. output projection (quant-aware MFMA) -> fp32 d_out
  gemm_q<false><<<256, 256, 0, stream>>>(x_q, s_x, woh, wol, b_out,
                                         y, nullptr, nullptr, 4096, 1024, 1024);
}